// Round 5
// baseline (201.145 us; speedup 1.0000x reference)
//
#include <hip/hip_runtime.h>
#include <hip/hip_bf16.h>

#define Bn 2
#define Sn 4096
#define Dn 512
#define Hn 8

typedef _Float16 f16x8 __attribute__((ext_vector_type(8)));
typedef __fp16 fp16x2 __attribute__((ext_vector_type(2)));
typedef float f32x16 __attribute__((ext_vector_type(16)));
typedef unsigned uint2v __attribute__((ext_vector_type(2)));

#if __has_builtin(__builtin_amdgcn_global_load_lds)
#define HAS_GLL 1
typedef const __attribute__((address_space(1))) unsigned int* gas1_t;
typedef __attribute__((address_space(3))) unsigned int* las3_t;
// async 16B/lane global->LDS: LDS dst = uniform base + lane*16
static __device__ __forceinline__ void ld_lds16(const void* g, void* l) {
    __builtin_amdgcn_global_load_lds((gas1_t)g, (las3_t)l, 16, 0, 0);
}
#else
#define HAS_GLL 0
#endif

// pack two f32 -> two f16 in one dword (v_cvt_pkrtz_f16_f32, 1 VALU op)
static __device__ __forceinline__ unsigned pkh(float a, float b) {
    union { fp16x2 h; unsigned u; } r;
    r.h = __builtin_amdgcn_cvt_pkrtz(a, b);
    return r.u;
}

// C-layout group pair -> A/B-fragment (K=16 shapes) via lane^32 exchange.
static __device__ __forceinline__ f16x8 xchg2(unsigned g0x, unsigned g0y,
                                              unsigned g1x, unsigned g1y, int hi) {
    union { unsigned u[4]; f16x8 v; } f;
#if __has_builtin(__builtin_amdgcn_permlane32_swap)
    uint2v rx = __builtin_amdgcn_permlane32_swap(g0x, g1x, false, false);
    uint2v ry = __builtin_amdgcn_permlane32_swap(g0y, g1y, false, false);
    f.u[0] = rx.x; f.u[1] = ry.x; f.u[2] = rx.y; f.u[3] = ry.y;
#else
    int sx = hi ? (int)g0x : (int)g1x;
    int sy = hi ? (int)g0y : (int)g1y;
    int rx = __shfl_xor(sx, 32);
    int ry = __shfl_xor(sy, 32);
    unsigned ox = hi ? g1x : g0x;
    unsigned oy = hi ? g1y : g0y;
    f.u[0] = hi ? (unsigned)rx : ox;
    f.u[1] = hi ? (unsigned)ry : oy;
    f.u[2] = hi ? ox : (unsigned)rx;
    f.u[3] = hi ? oy : (unsigned)ry;
#endif
    return f.v;
}

// ---------- unified prepass: K,V,W fp32 -> fragment-ordered f16 ----------
__global__ __launch_bounds__(256) void prep_kernel(
    const float* __restrict__ K, const float* __restrict__ V, const float* __restrict__ W,
    unsigned short* __restrict__ Kb, unsigned short* __restrict__ Vb,
    unsigned short* __restrict__ Wb) {
    const int vb = blockIdx.x;
    const int tid = threadIdx.x;
    if (vb < 1024) {
        const int kt = vb & 63, bh = vb >> 6;
        const int b = bh >> 3, h = bh & 7;
        unsigned short* dst = Kb + ((size_t)bh * 64 + kt) * 4096;
#pragma unroll
        for (int i = 0; i < 2; ++i) {
            int c = tid + i * 256;
            int f = c >> 6, ln = c & 63;
            int ktile = f >> 2, ks = f & 3;
            int row = ktile * 32 + (ln & 31);
            int dk = ks * 16 + (ln >> 5) * 8;
            const float* src = K + ((size_t)(b * Sn + kt * 64 + row)) * Dn + h * 64 + dk;
            float4 a0 = *(const float4*)src;
            float4 a1 = *(const float4*)(src + 4);
            uint4 o;
            o.x = pkh(a0.x, a0.y); o.y = pkh(a0.z, a0.w);
            o.z = pkh(a1.x, a1.y); o.w = pkh(a1.z, a1.w);
            *(uint4*)(dst + c * 8) = o;
        }
    } else if (vb < 2048) {
        const int u = vb - 1024;
        const int kt = u & 63, bh = u >> 6;
        const int b = bh >> 3, h = bh & 7;
        unsigned short* dst = Vb + ((size_t)bh * 64 + kt) * 4096;
#pragma unroll
        for (int i = 0; i < 2; ++i) {
            int c = tid + i * 256;
            int f = c >> 6, ln = c & 63;
            int dt = f >> 2, ks = f & 3;
            int dk = dt * 32 + (ln & 31);
            int key0 = ks * 16 + (ln >> 5) * 8;
            const float* src = V + ((size_t)(b * Sn + kt * 64 + key0)) * Dn + h * 64 + dk;
            uint4 o;
            o.x = pkh(src[0 * Dn], src[1 * Dn]);
            o.y = pkh(src[2 * Dn], src[3 * Dn]);
            o.z = pkh(src[4 * Dn], src[5 * Dn]);
            o.w = pkh(src[6 * Dn], src[7 * Dn]);
            *(uint4*)(dst + c * 8) = o;
        }
    } else {
        int c = (vb - 2048) * 256 + tid;
        int ln = c & 63, f = c >> 6;
        int ntile = f >> 5, ks = f & 31;
        int n = ntile * 32 + (ln & 31);
        int k0 = ks * 16 + (ln >> 5) * 8;
        uint4 o;
        o.x = pkh(W[(size_t)(k0 + 0) * Dn + n], W[(size_t)(k0 + 1) * Dn + n]);
        o.y = pkh(W[(size_t)(k0 + 2) * Dn + n], W[(size_t)(k0 + 3) * Dn + n]);
        o.z = pkh(W[(size_t)(k0 + 4) * Dn + n], W[(size_t)(k0 + 5) * Dn + n]);
        o.w = pkh(W[(size_t)(k0 + 6) * Dn + n], W[(size_t)(k0 + 7) * Dn + n]);
        *(uint4*)(Wb + c * 8) = o;
    }
}

// ---------- flash attention: K-frags prefetched from global (1 iter ahead), V via LDS ----------
// R0 structure: 512 thr = 8 waves; waves 0-3 keys 0..2047, waves 4-7 keys 2048..4095;
// wave pair (w4, w4+4) shares q-tile; pair-reduce via LDS at end.
// vs R4 (which regressed): K loads for tile it+1 are issued AFTER QK(it) has
// consumed the kf registers, so the ~200cyc L2 latency hides under exp+PV
// (~1500cyc) instead of stalling the QK MFMAs at the iteration top.
// Keeps R4's traffic win (FETCH 74->21 MB: XCD-clustered bh -> K/V L2/L3-hot)
// and halved LDS-pipe demand (V only), at R0's 4 waves/SIMD TLP.
__global__ __launch_bounds__(512, 4) void attn_kernel(
    const float* __restrict__ Q,
    const unsigned short* __restrict__ Kb,
    const unsigned short* __restrict__ Vb,
    unsigned short* __restrict__ ObA) {   // [gmtile 256][ksg 32][lane 64][8]
    // V double buffer: buf b at b*8192 ushorts (half*4096 within buf).
    // +1024 ushorts so the pair-reduce epilogue's 8448 floats fit.
    __shared__ __align__(16) unsigned short Vs[17408];  // 34 KB

    // XCD-aware remap of (qt, bh): linear id = x + 32*y; XCD = id%8 (round-robin).
    // bh = (id&7) + 8*(id>=256) -> all 32 qt-blocks of one bh land on one XCD.
    const int id = blockIdx.x + (blockIdx.y << 5);
    const int qt = (id >> 3) & 31;
    const int bh = (id & 7) + ((id >> 8) << 3);
    const int b = bh >> 3, h = bh & 7;
    const int tid = threadIdx.x;
    const int wg = tid >> 6;
    const int half = wg >> 2;
    const int w4 = wg & 3;
    const int lane = tid & 63;
    const int q = lane & 31;
    const int hi = lane >> 5;
    const int q0 = qt * 128 + w4 * 32;
    const float cexp = 0.18033688f;  // (1/sqrt(64)) * log2(e), folded into Q

    // Q B-frags (K=16): col=q, k(dk) = ks*16 + hi*8 + j
    f16x8 qf[4];
    {
        const float* qp = Q + ((size_t)(b * Sn + q0 + q)) * Dn + h * 64 + hi * 8;
#pragma unroll
        for (int ks = 0; ks < 4; ++ks) {
            float4 a0 = *(const float4*)(qp + ks * 16);
            float4 a1 = *(const float4*)(qp + ks * 16 + 4);
            union { unsigned u[4]; f16x8 v; } f;
            f.u[0] = pkh(a0.x * cexp, a0.y * cexp);
            f.u[1] = pkh(a0.z * cexp, a0.w * cexp);
            f.u[2] = pkh(a1.x * cexp, a1.y * cexp);
            f.u[3] = pkh(a1.z * cexp, a1.w * cexp);
            qf[ks] = f.v;
        }
    }

    f32x16 zf;
#pragma unroll
    for (int r = 0; r < 16; ++r) zf[r] = 0.f;
    f32x16 oacc[2];
    oacc[0] = zf; oacc[1] = zf;
    float l_ = 0.f;

    const size_t tbase = ((size_t)bh * 64 + half * 32) * 4096;
    // K fragment base for this wave (per-lane): frag f of tile it at + it*4096 + f*512
    const unsigned short* kg = Kb + tbase + lane * 8;
    // V staging: wave w4 covers ushorts [w4*1024, w4*1024+1024) of its half's tile
    const unsigned short* vgw = Vb + tbase + w4 * 1024;
    const int lV = half * 4096 + w4 * 1024;   // ushort offset within a buffer

#if HAS_GLL
#define STAGE_V(itx, bb) { \
    const unsigned short* vsp = vgw + (size_t)(itx) * 4096 + lane * 8; \
    unsigned short* lv = &Vs[(bb) * 8192 + lV]; \
    ld_lds16(vsp, lv); ld_lds16(vsp + 512, lv + 512); }
#else
    const int th = tid & 255;
#define STAGE_V(itx, bb) { \
    const unsigned short* vsp = vgw - (size_t)w4 * 1024 + (size_t)(itx) * 4096; \
    uint4 a2 = *(const uint4*)(vsp + th * 8); \
    uint4 a3 = *(const uint4*)(vsp + 2048 + th * 8); \
    unsigned short* lv = &Vs[(bb) * 8192 + half * 4096]; \
    *(uint4*)&lv[th * 8] = a2; *(uint4*)&lv[2048 + th * 8] = a3; }
#endif

    STAGE_V(0, 0);
    // prefetch K fragments for tile 0 (registers; L2-hot after prep)
    f16x8 kf0 = *(const f16x8*)(kg + 0 * 512);
    f16x8 kf1 = *(const f16x8*)(kg + 1 * 512);
    f16x8 kf2 = *(const f16x8*)(kg + 2 * 512);
    f16x8 kf3 = *(const f16x8*)(kg + 3 * 512);
    f16x8 kf4 = *(const f16x8*)(kg + 4 * 512);
    f16x8 kf5 = *(const f16x8*)(kg + 5 * 512);
    f16x8 kf6 = *(const f16x8*)(kg + 6 * 512);
    f16x8 kf7 = *(const f16x8*)(kg + 7 * 512);

    for (int it = 0; it < 32; ++it) {
        __syncthreads();   // drains staging; V buf[it&1] complete; prev readers done
        const unsigned short* Vbuf = Vs + (it & 1) * 8192 + half * 4096;
        if (it < 31) STAGE_V(it + 1, (it + 1) & 1);

        // S^T with current kf (loaded one iteration ago -> latency already paid)
        f32x16 sa0, sa1;
        sa0 = __builtin_amdgcn_mfma_f32_32x32x16_f16(kf0, qf[0], zf, 0, 0, 0);
        sa1 = __builtin_amdgcn_mfma_f32_32x32x16_f16(kf4, qf[0], zf, 0, 0, 0);
        sa0 = __builtin_amdgcn_mfma_f32_32x32x16_f16(kf1, qf[1], sa0, 0, 0, 0);
        sa1 = __builtin_amdgcn_mfma_f32_32x32x16_f16(kf5, qf[1], sa1, 0, 0, 0);
        sa0 = __builtin_amdgcn_mfma_f32_32x32x16_f16(kf2, qf[2], sa0, 0, 0, 0);
        sa1 = __builtin_amdgcn_mfma_f32_32x32x16_f16(kf6, qf[2], sa1, 0, 0, 0);
        sa0 = __builtin_amdgcn_mfma_f32_32x32x16_f16(kf3, qf[3], sa0, 0, 0, 0);
        sa1 = __builtin_amdgcn_mfma_f32_32x32x16_f16(kf7, qf[3], sa1, 0, 0, 0);

        // issue K prefetch for tile it+1 (WAR on kf regs: MFMAs above already
        // issued in-order; loads land during exp/PV below -> latency hidden)
        if (it < 31) {
            const unsigned short* kn = kg + (size_t)(it + 1) * 4096;
            kf0 = *(const f16x8*)(kn + 0 * 512);
            kf1 = *(const f16x8*)(kn + 1 * 512);
            kf2 = *(const f16x8*)(kn + 2 * 512);
            kf3 = *(const f16x8*)(kn + 3 * 512);
            kf4 = *(const f16x8*)(kn + 4 * 512);
            kf5 = *(const f16x8*)(kn + 5 * 512);
            kf6 = *(const f16x8*)(kn + 6 * 512);
            kf7 = *(const f16x8*)(kn + 7 * 512);
        }

        // p = exp2(s); lane-local l
        float e0[16], e1[16];
        float s0 = 0.f, s1 = 0.f;
#pragma unroll
        for (int r = 0; r < 16; ++r) { e0[r] = __builtin_amdgcn_exp2f(sa0[r]); s0 += e0[r]; }
#pragma unroll
        for (int r = 0; r < 16; ++r) { e1[r] = __builtin_amdgcn_exp2f(sa1[r]); s1 += e1[r]; }
        l_ += s0 + s1;

        // O^T += V^T . P^T  (K=16: B-frags from C-groups via permlane32_swap)
#pragma unroll
        for (int kp = 0; kp < 4; ++kp) {
            const float* e = (kp < 2) ? e0 : e1;
            const int s2 = kp & 1;
            unsigned g0x = pkh(e[8 * s2 + 0], e[8 * s2 + 1]);
            unsigned g0y = pkh(e[8 * s2 + 2], e[8 * s2 + 3]);
            unsigned g1x = pkh(e[8 * s2 + 4], e[8 * s2 + 5]);
            unsigned g1y = pkh(e[8 * s2 + 6], e[8 * s2 + 7]);
            f16x8 pb = xchg2(g0x, g0y, g1x, g1y, hi);
            f16x8 va0 = *(const f16x8*)&Vbuf[(0 + kp) * 512 + lane * 8];
            f16x8 va1 = *(const f16x8*)&Vbuf[(4 + kp) * 512 + lane * 8];
            oacc[0] = __builtin_amdgcn_mfma_f32_32x32x16_f16(va0, pb, oacc[0], 0, 0, 0);
            oacc[1] = __builtin_amdgcn_mfma_f32_32x32x16_f16(va1, pb, oacc[1], 0, 0, 0);
        }
    }

    // pair reduction through LDS (reuse Vs: rp = 8192 floats, Ls at float ofs 8192)
    __syncthreads();
    float* rp = (float*)Vs + w4 * 2048;
    float* Ls = (float*)Vs + 8192 + w4 * 64;
    if (half) {
#pragma unroll
        for (int g = 0; g < 8; ++g) {
            float4 v;
            v.x = oacc[g >> 2][(g & 3) * 4 + 0];
            v.y = oacc[g >> 2][(g & 3) * 4 + 1];
            v.z = oacc[g >> 2][(g & 3) * 4 + 2];
            v.w = oacc[g >> 2][(g & 3) * 4 + 3];
            *(float4*)&rp[g * 256 + lane * 4] = v;
        }
        Ls[lane] = l_;
    }
    __syncthreads();
    if (!half) {
#pragma unroll
        for (int g = 0; g < 8; ++g) {
            float4 v = *(const float4*)&rp[g * 256 + lane * 4];
            oacc[g >> 2][(g & 3) * 4 + 0] += v.x;
            oacc[g >> 2][(g & 3) * 4 + 1] += v.y;
            oacc[g >> 2][(g & 3) * 4 + 2] += v.z;
            oacc[g >> 2][(g & 3) * 4 + 3] += v.w;
        }
        l_ += Ls[lane];
        l_ += __shfl_xor(l_, 32);
        const float li = 1.f / l_;
        const int gm = b * 128 + qt * 4 + w4;
#pragma unroll
        for (int ksg = 0; ksg < 4; ++ksg) {
            const int dt = ksg >> 1, k2 = ksg & 1;
            unsigned g0x = pkh(oacc[dt][8 * k2 + 0] * li, oacc[dt][8 * k2 + 1] * li);
            unsigned g0y = pkh(oacc[dt][8 * k2 + 2] * li, oacc[dt][8 * k2 + 3] * li);
            unsigned g1x = pkh(oacc[dt][8 * k2 + 4] * li, oacc[dt][8 * k2 + 5] * li);
            unsigned g1y = pkh(oacc[dt][8 * k2 + 6] * li, oacc[dt][8 * k2 + 7] * li);
            f16x8 frag = xchg2(g0x, g0y, g1x, g1y, hi);
            union { f16x8 v; uint4 u; } fu; fu.v = frag;
            *(uint4*)&ObA[((size_t)(gm * 32 + h * 4 + ksg) * 64 + lane) * 8] = fu.u;
        }
    }
}

// ---------- projection GEMM: out = A @ W + b (A,W fragment-ordered f16) ----------
__global__ __launch_bounds__(256) void proj_kernel(
    const unsigned short* __restrict__ ObA,  // [256][32][64][8]
    const unsigned short* __restrict__ Wb,   // [16][32][64][8]
    const float* __restrict__ bias,
    float* __restrict__ out) {
    __shared__ __align__(16) unsigned short Ash[8192];
    __shared__ __align__(16) unsigned short Wsh[4096];

    const int mt = blockIdx.x;
    const int nt = blockIdx.y;
    const int tid = threadIdx.x;
    const int w = tid >> 6;
    const int lane = tid & 63;
    const int q = lane & 31;
    const int hi = lane >> 5;

    f32x16 acc[2];
#pragma unroll
    for (int t = 0; t < 2; ++t)
#pragma unroll
        for (int r = 0; r < 16; ++r) acc[t][r] = 0.f;

    for (int kt = 0; kt < 8; ++kt) {
        __syncthreads();
#pragma unroll
        for (int i = 0; i < 4; ++i) {
            int ci = (tid >> 6) + i * 4;
            int ml = ci >> 2, ksl = ci & 3;
            *(uint4*)&Ash[ci * 512 + lane * 8] =
                *(const uint4*)(ObA + (((size_t)(mt * 4 + ml) * 32 + kt * 4 + ksl) * 64 + lane) * 8);
        }
#pragma unroll
        for (int i = 0; i < 2; ++i) {
            int ci = (tid >> 6) + i * 4;
            int ntl = ci >> 2, ksl = ci & 3;
            *(uint4*)&Wsh[ci * 512 + lane * 8] =
                *(const uint4*)(Wb + (((size_t)(nt * 2 + ntl) * 32 + kt * 4 + ksl) * 64 + lane) * 8);
        }
        __syncthreads();

#pragma unroll
        for (int ks = 0; ks < 4; ++ks) {
            f16x8 a  = *(const f16x8*)&Ash[(w * 4 + ks) * 512 + lane * 8];
            f16x8 b0 = *(const f16x8*)&Wsh[(0 * 4 + ks) * 512 + lane * 8];
            f16x8 b1 = *(const f16x8*)&Wsh[(4 + ks) * 512 + lane * 8];
            acc[0] = __builtin_amdgcn_mfma_f32_32x32x16_f16(a, b0, acc[0], 0, 0, 0);
            acc[1] = __builtin_amdgcn_mfma_f32_32x32x16_f16(a, b1, acc[1], 0, 0, 0);
        }
    }

#pragma unroll
    for (int ntl = 0; ntl < 2; ++ntl) {
        int col = nt * 64 + ntl * 32 + q;
        float bv = bias[col];
#pragma unroll
        for (int reg = 0; reg < 16; ++reg) {
            int row = mt * 128 + w * 32 + (reg & 3) + 8 * (reg >> 2) + 4 * hi;
            out[(size_t)row * Dn + col] = acc[ntl][reg] + bv;
        }
    }
}

extern "C" void kernel_launch(void* const* d_in, const int* in_sizes, int n_in,
                              void* d_out, int out_size, void* d_ws, size_t ws_size,
                              hipStream_t stream) {
    const float* Q = (const float*)d_in[0];
    const float* K = (const float*)d_in[1];
    const float* V = (const float*)d_in[2];
    const float* W = (const float*)d_in[3];
    const float* bo = (const float*)d_in[4];
    float* out = (float*)d_out;

    char* ws = (char*)d_ws;
    unsigned short* Kb  = (unsigned short*)(ws);                 // 8 MB
    unsigned short* Vb  = (unsigned short*)(ws + 8388608);       // 8 MB
    unsigned short* Wb  = (unsigned short*)(ws + 16777216);      // 512 KB
    unsigned short* ObA = (unsigned short*)(ws + 17301504);      // 8 MB

    prep_kernel<<<2176, 256, 0, stream>>>(K, V, W, Kb, Vb, Wb);
    attn_kernel<<<dim3(32, 16), 512, 0, stream>>>(Q, Kb, Vb, ObA);
    proj_kernel<<<dim3(64, 8), 256, 0, stream>>>(ObA, Wb, bo, out);
}

// Round 6
// 186.522 us; speedup vs baseline: 1.0784x; 1.0784x over previous
//
#include <hip/hip_runtime.h>
#include <hip/hip_bf16.h>

#define Bn 2
#define Sn 4096
#define Dn 512
#define Hn 8

typedef _Float16 f16x8 __attribute__((ext_vector_type(8)));
typedef __fp16 fp16x2 __attribute__((ext_vector_type(2)));
typedef float f32x16 __attribute__((ext_vector_type(16)));
typedef unsigned uint2v __attribute__((ext_vector_type(2)));

#if __has_builtin(__builtin_amdgcn_global_load_lds)
#define HAS_GLL 1
typedef const __attribute__((address_space(1))) unsigned int* gas1_t;
typedef __attribute__((address_space(3))) unsigned int* las3_t;
// async 16B/lane global->LDS: LDS dst = uniform base + lane*16
static __device__ __forceinline__ void ld_lds16(const void* g, void* l) {
    __builtin_amdgcn_global_load_lds((gas1_t)g, (las3_t)l, 16, 0, 0);
}
#else
#define HAS_GLL 0
#endif

// pack two f32 -> two f16 in one dword (v_cvt_pkrtz_f16_f32, 1 VALU op)
static __device__ __forceinline__ unsigned pkh(float a, float b) {
    union { fp16x2 h; unsigned u; } r;
    r.h = __builtin_amdgcn_cvt_pkrtz(a, b);
    return r.u;
}

// C-layout group pair -> A/B-fragment (K=16 shapes) via lane^32 exchange.
static __device__ __forceinline__ f16x8 xchg2(unsigned g0x, unsigned g0y,
                                              unsigned g1x, unsigned g1y, int hi) {
    union { unsigned u[4]; f16x8 v; } f;
#if __has_builtin(__builtin_amdgcn_permlane32_swap)
    uint2v rx = __builtin_amdgcn_permlane32_swap(g0x, g1x, false, false);
    uint2v ry = __builtin_amdgcn_permlane32_swap(g0y, g1y, false, false);
    f.u[0] = rx.x; f.u[1] = ry.x; f.u[2] = rx.y; f.u[3] = ry.y;
#else
    int sx = hi ? (int)g0x : (int)g1x;
    int sy = hi ? (int)g0y : (int)g1y;
    int rx = __shfl_xor(sx, 32);
    int ry = __shfl_xor(sy, 32);
    unsigned ox = hi ? g1x : g0x;
    unsigned oy = hi ? g1y : g0y;
    f.u[0] = hi ? (unsigned)rx : ox;
    f.u[1] = hi ? (unsigned)ry : oy;
    f.u[2] = hi ? ox : (unsigned)rx;
    f.u[3] = hi ? oy : (unsigned)ry;
#endif
    return f.v;
}

// ---------- unified prepass: K,V,W fp32 -> fragment-ordered f16 ----------
__global__ __launch_bounds__(256) void prep_kernel(
    const float* __restrict__ K, const float* __restrict__ V, const float* __restrict__ W,
    unsigned short* __restrict__ Kb, unsigned short* __restrict__ Vb,
    unsigned short* __restrict__ Wb) {
    const int vb = blockIdx.x;
    const int tid = threadIdx.x;
    if (vb < 1024) {
        const int kt = vb & 63, bh = vb >> 6;
        const int b = bh >> 3, h = bh & 7;
        unsigned short* dst = Kb + ((size_t)bh * 64 + kt) * 4096;
#pragma unroll
        for (int i = 0; i < 2; ++i) {
            int c = tid + i * 256;
            int f = c >> 6, ln = c & 63;
            int ktile = f >> 2, ks = f & 3;
            int row = ktile * 32 + (ln & 31);
            int dk = ks * 16 + (ln >> 5) * 8;
            const float* src = K + ((size_t)(b * Sn + kt * 64 + row)) * Dn + h * 64 + dk;
            float4 a0 = *(const float4*)src;
            float4 a1 = *(const float4*)(src + 4);
            uint4 o;
            o.x = pkh(a0.x, a0.y); o.y = pkh(a0.z, a0.w);
            o.z = pkh(a1.x, a1.y); o.w = pkh(a1.z, a1.w);
            *(uint4*)(dst + c * 8) = o;
        }
    } else if (vb < 2048) {
        const int u = vb - 1024;
        const int kt = u & 63, bh = u >> 6;
        const int b = bh >> 3, h = bh & 7;
        unsigned short* dst = Vb + ((size_t)bh * 64 + kt) * 4096;
#pragma unroll
        for (int i = 0; i < 2; ++i) {
            int c = tid + i * 256;
            int f = c >> 6, ln = c & 63;
            int dt = f >> 2, ks = f & 3;
            int dk = dt * 32 + (ln & 31);
            int key0 = ks * 16 + (ln >> 5) * 8;
            const float* src = V + ((size_t)(b * Sn + kt * 64 + key0)) * Dn + h * 64 + dk;
            uint4 o;
            o.x = pkh(src[0 * Dn], src[1 * Dn]);
            o.y = pkh(src[2 * Dn], src[3 * Dn]);
            o.z = pkh(src[4 * Dn], src[5 * Dn]);
            o.w = pkh(src[6 * Dn], src[7 * Dn]);
            *(uint4*)(dst + c * 8) = o;
        }
    } else {
        int c = (vb - 2048) * 256 + tid;
        int ln = c & 63, f = c >> 6;
        int ntile = f >> 5, ks = f & 31;
        int n = ntile * 32 + (ln & 31);
        int k0 = ks * 16 + (ln >> 5) * 8;
        uint4 o;
        o.x = pkh(W[(size_t)(k0 + 0) * Dn + n], W[(size_t)(k0 + 1) * Dn + n]);
        o.y = pkh(W[(size_t)(k0 + 2) * Dn + n], W[(size_t)(k0 + 3) * Dn + n]);
        o.z = pkh(W[(size_t)(k0 + 4) * Dn + n], W[(size_t)(k0 + 5) * Dn + n]);
        o.w = pkh(W[(size_t)(k0 + 6) * Dn + n], W[(size_t)(k0 + 7) * Dn + n]);
        *(uint4*)(Wb + c * 8) = o;
    }
}

// ---------- flash attention: K-frags prefetched from global (1 iter ahead), V via LDS ----------
// 512 thr = 8 waves; waves 0-3 keys 0..2047, waves 4-7 keys 2048..4095;
// wave pair (w4, w4+4) shares q-tile; pair-reduce via LDS at end.
// vs R5 (spill-bound): __launch_bounds__(512,2) lifts the VGPR cap 64->128
// (grid is 512 blocks = 2 blocks/CU anyway, so no occupancy loss), and
// exp2+pack are fused (16 packed dwords instead of 32 live floats) so the
// kf prefetch + oacc + qf state fits without scratch. R4/R5's WRITE_SIZE
// 18-26MB (vs 9MB ObA) was spill traffic - that is the thing being removed.
__global__ __launch_bounds__(512, 2) void attn_kernel(
    const float* __restrict__ Q,
    const unsigned short* __restrict__ Kb,
    const unsigned short* __restrict__ Vb,
    unsigned short* __restrict__ ObA) {   // [gmtile 256][ksg 32][lane 64][8]
    // V double buffer: buf b at b*8192 ushorts (half*4096 within buf).
    // +1024 ushorts so the pair-reduce epilogue's 8448 floats fit.
    __shared__ __align__(16) unsigned short Vs[17408];  // 34 KB

    // XCD-aware remap of (qt, bh): linear id = x + 32*y; XCD = id%8 (round-robin).
    // bh = (id&7) + 8*(id>=256) -> all 32 qt-blocks of one bh land on one XCD.
    const int id = blockIdx.x + (blockIdx.y << 5);
    const int qt = (id >> 3) & 31;
    const int bh = (id & 7) + ((id >> 8) << 3);
    const int b = bh >> 3, h = bh & 7;
    const int tid = threadIdx.x;
    const int wg = tid >> 6;
    const int half = wg >> 2;
    const int w4 = wg & 3;
    const int lane = tid & 63;
    const int q = lane & 31;
    const int hi = lane >> 5;
    const int q0 = qt * 128 + w4 * 32;
    const float cexp = 0.18033688f;  // (1/sqrt(64)) * log2(e), folded into Q

    // Q B-frags (K=16): col=q, k(dk) = ks*16 + hi*8 + j
    f16x8 qf[4];
    {
        const float* qp = Q + ((size_t)(b * Sn + q0 + q)) * Dn + h * 64 + hi * 8;
#pragma unroll
        for (int ks = 0; ks < 4; ++ks) {
            float4 a0 = *(const float4*)(qp + ks * 16);
            float4 a1 = *(const float4*)(qp + ks * 16 + 4);
            union { unsigned u[4]; f16x8 v; } f;
            f.u[0] = pkh(a0.x * cexp, a0.y * cexp);
            f.u[1] = pkh(a0.z * cexp, a0.w * cexp);
            f.u[2] = pkh(a1.x * cexp, a1.y * cexp);
            f.u[3] = pkh(a1.z * cexp, a1.w * cexp);
            qf[ks] = f.v;
        }
    }

    f32x16 zf;
#pragma unroll
    for (int r = 0; r < 16; ++r) zf[r] = 0.f;
    f32x16 oacc[2];
    oacc[0] = zf; oacc[1] = zf;
    float l_ = 0.f;

    const size_t tbase = ((size_t)bh * 64 + half * 32) * 4096;
    // K fragment base for this wave (per-lane): frag f of tile it at + it*4096 + f*512
    const unsigned short* kg = Kb + tbase + lane * 8;
    // V staging: wave w4 covers ushorts [w4*1024, w4*1024+1024) of its half's tile
    const unsigned short* vgw = Vb + tbase + w4 * 1024;
    const int lV = half * 4096 + w4 * 1024;   // ushort offset within a buffer

#if HAS_GLL
#define STAGE_V(itx, bb) { \
    const unsigned short* vsp = vgw + (size_t)(itx) * 4096 + lane * 8; \
    unsigned short* lv = &Vs[(bb) * 8192 + lV]; \
    ld_lds16(vsp, lv); ld_lds16(vsp + 512, lv + 512); }
#else
    const int th = tid & 255;
#define STAGE_V(itx, bb) { \
    const unsigned short* vsp = vgw - (size_t)w4 * 1024 + (size_t)(itx) * 4096; \
    uint4 a2 = *(const uint4*)(vsp + th * 8); \
    uint4 a3 = *(const uint4*)(vsp + 2048 + th * 8); \
    unsigned short* lv = &Vs[(bb) * 8192 + half * 4096]; \
    *(uint4*)&lv[th * 8] = a2; *(uint4*)&lv[2048 + th * 8] = a3; }
#endif

    STAGE_V(0, 0);
    // prefetch K fragments for tile 0 (registers; L2-hot after prep)
    f16x8 kf0 = *(const f16x8*)(kg + 0 * 512);
    f16x8 kf1 = *(const f16x8*)(kg + 1 * 512);
    f16x8 kf2 = *(const f16x8*)(kg + 2 * 512);
    f16x8 kf3 = *(const f16x8*)(kg + 3 * 512);
    f16x8 kf4 = *(const f16x8*)(kg + 4 * 512);
    f16x8 kf5 = *(const f16x8*)(kg + 5 * 512);
    f16x8 kf6 = *(const f16x8*)(kg + 6 * 512);
    f16x8 kf7 = *(const f16x8*)(kg + 7 * 512);

    for (int it = 0; it < 32; ++it) {
        __syncthreads();   // drains staging; V buf[it&1] complete; prev readers done
        const unsigned short* Vbuf = Vs + (it & 1) * 8192 + half * 4096;
        if (it < 31) STAGE_V(it + 1, (it + 1) & 1);

        // S^T with current kf (loaded one iteration ago -> latency already paid)
        f32x16 sa0, sa1;
        sa0 = __builtin_amdgcn_mfma_f32_32x32x16_f16(kf0, qf[0], zf, 0, 0, 0);
        sa1 = __builtin_amdgcn_mfma_f32_32x32x16_f16(kf4, qf[0], zf, 0, 0, 0);
        sa0 = __builtin_amdgcn_mfma_f32_32x32x16_f16(kf1, qf[1], sa0, 0, 0, 0);
        sa1 = __builtin_amdgcn_mfma_f32_32x32x16_f16(kf5, qf[1], sa1, 0, 0, 0);
        sa0 = __builtin_amdgcn_mfma_f32_32x32x16_f16(kf2, qf[2], sa0, 0, 0, 0);
        sa1 = __builtin_amdgcn_mfma_f32_32x32x16_f16(kf6, qf[2], sa1, 0, 0, 0);
        sa0 = __builtin_amdgcn_mfma_f32_32x32x16_f16(kf3, qf[3], sa0, 0, 0, 0);
        sa1 = __builtin_amdgcn_mfma_f32_32x32x16_f16(kf7, qf[3], sa1, 0, 0, 0);

        // issue K prefetch for tile it+1 (WAR on kf regs; loads land during
        // exp/PV below -> ~200cyc L2 latency hidden under ~1500cyc of work)
        if (it < 31) {
            const unsigned short* kn = kg + (size_t)(it + 1) * 4096;
            kf0 = *(const f16x8*)(kn + 0 * 512);
            kf1 = *(const f16x8*)(kn + 1 * 512);
            kf2 = *(const f16x8*)(kn + 2 * 512);
            kf3 = *(const f16x8*)(kn + 3 * 512);
            kf4 = *(const f16x8*)(kn + 4 * 512);
            kf5 = *(const f16x8*)(kn + 5 * 512);
            kf6 = *(const f16x8*)(kn + 6 * 512);
            kf7 = *(const f16x8*)(kn + 7 * 512);
        }

        // p = exp2(s) fused with f16 pack: only 16 packed dwords live
        // (vs 32 floats) -> fits the 128-VGPR budget without scratch
        unsigned u0[8], u1[8];
        float s0 = 0.f, s1 = 0.f;
#pragma unroll
        for (int j = 0; j < 8; ++j) {
            float ea = __builtin_amdgcn_exp2f(sa0[2 * j]);
            float eb = __builtin_amdgcn_exp2f(sa0[2 * j + 1]);
            s0 += ea + eb;
            u0[j] = pkh(ea, eb);
        }
#pragma unroll
        for (int j = 0; j < 8; ++j) {
            float ea = __builtin_amdgcn_exp2f(sa1[2 * j]);
            float eb = __builtin_amdgcn_exp2f(sa1[2 * j + 1]);
            s1 += ea + eb;
            u1[j] = pkh(ea, eb);
        }
        l_ += s0 + s1;

        // O^T += V^T . P^T  (K=16: B-frags from packed C-groups via permlane32_swap)
#pragma unroll
        for (int kp = 0; kp < 4; ++kp) {
            const unsigned* u = (kp < 2) ? u0 : u1;
            const int s2 = kp & 1;
            f16x8 pb = xchg2(u[4 * s2 + 0], u[4 * s2 + 1], u[4 * s2 + 2], u[4 * s2 + 3], hi);
            f16x8 va0 = *(const f16x8*)&Vbuf[(0 + kp) * 512 + lane * 8];
            f16x8 va1 = *(const f16x8*)&Vbuf[(4 + kp) * 512 + lane * 8];
            oacc[0] = __builtin_amdgcn_mfma_f32_32x32x16_f16(va0, pb, oacc[0], 0, 0, 0);
            oacc[1] = __builtin_amdgcn_mfma_f32_32x32x16_f16(va1, pb, oacc[1], 0, 0, 0);
        }
    }

    // pair reduction through LDS (reuse Vs: rp = 8192 floats, Ls at float ofs 8192)
    __syncthreads();
    float* rp = (float*)Vs + w4 * 2048;
    float* Ls = (float*)Vs + 8192 + w4 * 64;
    if (half) {
#pragma unroll
        for (int g = 0; g < 8; ++g) {
            float4 v;
            v.x = oacc[g >> 2][(g & 3) * 4 + 0];
            v.y = oacc[g >> 2][(g & 3) * 4 + 1];
            v.z = oacc[g >> 2][(g & 3) * 4 + 2];
            v.w = oacc[g >> 2][(g & 3) * 4 + 3];
            *(float4*)&rp[g * 256 + lane * 4] = v;
        }
        Ls[lane] = l_;
    }
    __syncthreads();
    if (!half) {
#pragma unroll
        for (int g = 0; g < 8; ++g) {
            float4 v = *(const float4*)&rp[g * 256 + lane * 4];
            oacc[g >> 2][(g & 3) * 4 + 0] += v.x;
            oacc[g >> 2][(g & 3) * 4 + 1] += v.y;
            oacc[g >> 2][(g & 3) * 4 + 2] += v.z;
            oacc[g >> 2][(g & 3) * 4 + 3] += v.w;
        }
        l_ += Ls[lane];
        l_ += __shfl_xor(l_, 32);
        const float li = 1.f / l_;
        const int gm = b * 128 + qt * 4 + w4;
#pragma unroll
        for (int ksg = 0; ksg < 4; ++ksg) {
            const int dt = ksg >> 1, k2 = ksg & 1;
            unsigned g0x = pkh(oacc[dt][8 * k2 + 0] * li, oacc[dt][8 * k2 + 1] * li);
            unsigned g0y = pkh(oacc[dt][8 * k2 + 2] * li, oacc[dt][8 * k2 + 3] * li);
            unsigned g1x = pkh(oacc[dt][8 * k2 + 4] * li, oacc[dt][8 * k2 + 5] * li);
            unsigned g1y = pkh(oacc[dt][8 * k2 + 6] * li, oacc[dt][8 * k2 + 7] * li);
            f16x8 frag = xchg2(g0x, g0y, g1x, g1y, hi);
            union { f16x8 v; uint4 u; } fu; fu.v = frag;
            *(uint4*)&ObA[((size_t)(gm * 32 + h * 4 + ksg) * 64 + lane) * 8] = fu.u;
        }
    }
}

// ---------- projection GEMM: out = A @ W + b (A,W fragment-ordered f16) ----------
__global__ __launch_bounds__(256) void proj_kernel(
    const unsigned short* __restrict__ ObA,  // [256][32][64][8]
    const unsigned short* __restrict__ Wb,   // [16][32][64][8]
    const float* __restrict__ bias,
    float* __restrict__ out) {
    __shared__ __align__(16) unsigned short Ash[8192];
    __shared__ __align__(16) unsigned short Wsh[4096];

    const int mt = blockIdx.x;
    const int nt = blockIdx.y;
    const int tid = threadIdx.x;
    const int w = tid >> 6;
    const int lane = tid & 63;
    const int q = lane & 31;
    const int hi = lane >> 5;

    f32x16 acc[2];
#pragma unroll
    for (int t = 0; t < 2; ++t)
#pragma unroll
        for (int r = 0; r < 16; ++r) acc[t][r] = 0.f;

    for (int kt = 0; kt < 8; ++kt) {
        __syncthreads();
#pragma unroll
        for (int i = 0; i < 4; ++i) {
            int ci = (tid >> 6) + i * 4;
            int ml = ci >> 2, ksl = ci & 3;
            *(uint4*)&Ash[ci * 512 + lane * 8] =
                *(const uint4*)(ObA + (((size_t)(mt * 4 + ml) * 32 + kt * 4 + ksl) * 64 + lane) * 8);
        }
#pragma unroll
        for (int i = 0; i < 2; ++i) {
            int ci = (tid >> 6) + i * 4;
            int ntl = ci >> 2, ksl = ci & 3;
            *(uint4*)&Wsh[ci * 512 + lane * 8] =
                *(const uint4*)(Wb + (((size_t)(nt * 2 + ntl) * 32 + kt * 4 + ksl) * 64 + lane) * 8);
        }
        __syncthreads();

#pragma unroll
        for (int ks = 0; ks < 4; ++ks) {
            f16x8 a  = *(const f16x8*)&Ash[(w * 4 + ks) * 512 + lane * 8];
            f16x8 b0 = *(const f16x8*)&Wsh[(0 * 4 + ks) * 512 + lane * 8];
            f16x8 b1 = *(const f16x8*)&Wsh[(4 + ks) * 512 + lane * 8];
            acc[0] = __builtin_amdgcn_mfma_f32_32x32x16_f16(a, b0, acc[0], 0, 0, 0);
            acc[1] = __builtin_amdgcn_mfma_f32_32x32x16_f16(a, b1, acc[1], 0, 0, 0);
        }
    }

#pragma unroll
    for (int ntl = 0; ntl < 2; ++ntl) {
        int col = nt * 64 + ntl * 32 + q;
        float bv = bias[col];
#pragma unroll
        for (int reg = 0; reg < 16; ++reg) {
            int row = mt * 128 + w * 32 + (reg & 3) + 8 * (reg >> 2) + 4 * hi;
            out[(size_t)row * Dn + col] = acc[ntl][reg] + bv;
        }
    }
}

extern "C" void kernel_launch(void* const* d_in, const int* in_sizes, int n_in,
                              void* d_out, int out_size, void* d_ws, size_t ws_size,
                              hipStream_t stream) {
    const float* Q = (const float*)d_in[0];
    const float* K = (const float*)d_in[1];
    const float* V = (const float*)d_in[2];
    const float* W = (const float*)d_in[3];
    const float* bo = (const float*)d_in[4];
    float* out = (float*)d_out;

    char* ws = (char*)d_ws;
    unsigned short* Kb  = (unsigned short*)(ws);                 // 8 MB
    unsigned short* Vb  = (unsigned short*)(ws + 8388608);       // 8 MB
    unsigned short* Wb  = (unsigned short*)(ws + 16777216);      // 512 KB
    unsigned short* ObA = (unsigned short*)(ws + 17301504);      // 8 MB

    prep_kernel<<<2176, 256, 0, stream>>>(K, V, W, Kb, Vb, Wb);
    attn_kernel<<<dim3(32, 16), 512, 0, stream>>>(Q, Kb, Vb, ObA);
    proj_kernel<<<dim3(64, 8), 256, 0, stream>>>(ObA, Wb, bo, out);
}

// Round 7
// 178.032 us; speedup vs baseline: 1.1298x; 1.0477x over previous
//
#include <hip/hip_runtime.h>
#include <hip/hip_bf16.h>

#define Bn 2
#define Sn 4096
#define Dn 512
#define Hn 8

typedef _Float16 f16x8 __attribute__((ext_vector_type(8)));
typedef __fp16 fp16x2 __attribute__((ext_vector_type(2)));
typedef float f32x16 __attribute__((ext_vector_type(16)));
typedef unsigned uint2v __attribute__((ext_vector_type(2)));

#if __has_builtin(__builtin_amdgcn_global_load_lds)
#define HAS_GLL 1
typedef const __attribute__((address_space(1))) unsigned int* gas1_t;
typedef __attribute__((address_space(3))) unsigned int* las3_t;
// async 16B/lane global->LDS: LDS dst = uniform base + lane*16
static __device__ __forceinline__ void ld_lds16(const void* g, void* l) {
    __builtin_amdgcn_global_load_lds((gas1_t)g, (las3_t)l, 16, 0, 0);
}
#else
#define HAS_GLL 0
#endif

// pack two f32 -> two f16 in one dword (v_cvt_pkrtz_f16_f32, 1 VALU op)
static __device__ __forceinline__ unsigned pkh(float a, float b) {
    union { fp16x2 h; unsigned u; } r;
    r.h = __builtin_amdgcn_cvt_pkrtz(a, b);
    return r.u;
}

// C-layout group pair -> A/B-fragment (K=16 shapes) via lane^32 exchange.
static __device__ __forceinline__ f16x8 xchg2(unsigned g0x, unsigned g0y,
                                              unsigned g1x, unsigned g1y, int hi) {
    union { unsigned u[4]; f16x8 v; } f;
#if __has_builtin(__builtin_amdgcn_permlane32_swap)
    uint2v rx = __builtin_amdgcn_permlane32_swap(g0x, g1x, false, false);
    uint2v ry = __builtin_amdgcn_permlane32_swap(g0y, g1y, false, false);
    f.u[0] = rx.x; f.u[1] = ry.x; f.u[2] = rx.y; f.u[3] = ry.y;
#else
    int sx = hi ? (int)g0x : (int)g1x;
    int sy = hi ? (int)g0y : (int)g1y;
    int rx = __shfl_xor(sx, 32);
    int ry = __shfl_xor(sy, 32);
    unsigned ox = hi ? g1x : g0x;
    unsigned oy = hi ? g1y : g0y;
    f.u[0] = hi ? (unsigned)rx : ox;
    f.u[1] = hi ? (unsigned)ry : oy;
    f.u[2] = hi ? ox : (unsigned)rx;
    f.u[3] = hi ? oy : (unsigned)ry;
#endif
    return f.v;
}

// ---------- unified prepass: K,V,W fp32 -> fragment-ordered f16 ----------
__global__ __launch_bounds__(256) void prep_kernel(
    const float* __restrict__ K, const float* __restrict__ V, const float* __restrict__ W,
    unsigned short* __restrict__ Kb, unsigned short* __restrict__ Vb,
    unsigned short* __restrict__ Wb) {
    const int vb = blockIdx.x;
    const int tid = threadIdx.x;
    if (vb < 1024) {
        const int kt = vb & 63, bh = vb >> 6;
        const int b = bh >> 3, h = bh & 7;
        unsigned short* dst = Kb + ((size_t)bh * 64 + kt) * 4096;
#pragma unroll
        for (int i = 0; i < 2; ++i) {
            int c = tid + i * 256;
            int f = c >> 6, ln = c & 63;
            int ktile = f >> 2, ks = f & 3;
            int row = ktile * 32 + (ln & 31);
            int dk = ks * 16 + (ln >> 5) * 8;
            const float* src = K + ((size_t)(b * Sn + kt * 64 + row)) * Dn + h * 64 + dk;
            float4 a0 = *(const float4*)src;
            float4 a1 = *(const float4*)(src + 4);
            uint4 o;
            o.x = pkh(a0.x, a0.y); o.y = pkh(a0.z, a0.w);
            o.z = pkh(a1.x, a1.y); o.w = pkh(a1.z, a1.w);
            *(uint4*)(dst + c * 8) = o;
        }
    } else if (vb < 2048) {
        const int u = vb - 1024;
        const int kt = u & 63, bh = u >> 6;
        const int b = bh >> 3, h = bh & 7;
        unsigned short* dst = Vb + ((size_t)bh * 64 + kt) * 4096;
#pragma unroll
        for (int i = 0; i < 2; ++i) {
            int c = tid + i * 256;
            int f = c >> 6, ln = c & 63;
            int dt = f >> 2, ks = f & 3;
            int dk = dt * 32 + (ln & 31);
            int key0 = ks * 16 + (ln >> 5) * 8;
            const float* src = V + ((size_t)(b * Sn + kt * 64 + key0)) * Dn + h * 64 + dk;
            uint4 o;
            o.x = pkh(src[0 * Dn], src[1 * Dn]);
            o.y = pkh(src[2 * Dn], src[3 * Dn]);
            o.z = pkh(src[4 * Dn], src[5 * Dn]);
            o.w = pkh(src[6 * Dn], src[7 * Dn]);
            *(uint4*)(dst + c * 8) = o;
        }
    } else {
        int c = (vb - 2048) * 256 + tid;
        int ln = c & 63, f = c >> 6;
        int ntile = f >> 5, ks = f & 31;
        int n = ntile * 32 + (ln & 31);
        int k0 = ks * 16 + (ln >> 5) * 8;
        uint4 o;
        o.x = pkh(W[(size_t)(k0 + 0) * Dn + n], W[(size_t)(k0 + 1) * Dn + n]);
        o.y = pkh(W[(size_t)(k0 + 2) * Dn + n], W[(size_t)(k0 + 3) * Dn + n]);
        o.z = pkh(W[(size_t)(k0 + 4) * Dn + n], W[(size_t)(k0 + 5) * Dn + n]);
        o.w = pkh(W[(size_t)(k0 + 6) * Dn + n], W[(size_t)(k0 + 7) * Dn + n]);
        *(uint4*)(Wb + c * 8) = o;
    }
}

// ---------- flash attention: 64 q-rows per wave (2x arithmetic intensity) ----------
// 256 thr = 4 waves: wave (half, qs). half = key range (0..2047 / 2048..4095),
// qs = 64-q-row subgroup. Each wave holds TWO q-tiles (qf0/qf1) and 2x2 oacc;
// each K-fragment ds_read feeds 2 QK MFMAs, each V-fragment 2 PV MFMAs ->
// 16KB LDS reads per 32 MFMAs (was per 16). Per-CU pipe demand per iter-slot:
// MFMA 2048cyc > LDS ~1200cyc > TA ~800cyc -> MFMA-bound for the first time
// (R0-R6 invariant: MfmaUtil*dur const ~3000 us*% -> stalls were data pipes).
// 2 blocks/CU (64KB LDS each); each SIMD gets 1 wave from each block ->
// independent barriers -> cross-wave MFMA/VALU overlap.
__global__ __launch_bounds__(256, 2) void attn_kernel(
    const float* __restrict__ Q,
    const unsigned short* __restrict__ Kb,
    const unsigned short* __restrict__ Vb,
    unsigned short* __restrict__ ObA) {   // [gmtile 256][ksg 32][lane 64][8]
    // [buf 2][half 2][ K 4096 | V 4096 ] ushorts = 64 KB
    __shared__ __align__(16) unsigned short KV[32768];

    const int qt = blockIdx.x;
    const int bh = blockIdx.y;
    const int b = bh >> 3, h = bh & 7;
    const int tid = threadIdx.x;
    const int wg = tid >> 6;
    const int half = wg >> 1;
    const int qs = wg & 1;
    const int lane = tid & 63;
    const int q = lane & 31;
    const int hi = lane >> 5;
    const float cexp = 0.18033688f;  // (1/sqrt(64)) * log2(e), folded into Q

    // Q B-frags for two q-tiles: rows qt*128 + qs*64 + t*32 + q
    f16x8 qf0[4], qf1[4];
    {
        const float* qp0 = Q + ((size_t)(b * Sn + qt * 128 + qs * 64 + q)) * Dn + h * 64 + hi * 8;
        const float* qp1 = qp0 + (size_t)32 * Dn;
#pragma unroll
        for (int ks = 0; ks < 4; ++ks) {
            float4 a0 = *(const float4*)(qp0 + ks * 16);
            float4 a1 = *(const float4*)(qp0 + ks * 16 + 4);
            union { unsigned u[4]; f16x8 v; } f;
            f.u[0] = pkh(a0.x * cexp, a0.y * cexp);
            f.u[1] = pkh(a0.z * cexp, a0.w * cexp);
            f.u[2] = pkh(a1.x * cexp, a1.y * cexp);
            f.u[3] = pkh(a1.z * cexp, a1.w * cexp);
            qf0[ks] = f.v;
            a0 = *(const float4*)(qp1 + ks * 16);
            a1 = *(const float4*)(qp1 + ks * 16 + 4);
            f.u[0] = pkh(a0.x * cexp, a0.y * cexp);
            f.u[1] = pkh(a0.z * cexp, a0.w * cexp);
            f.u[2] = pkh(a1.x * cexp, a1.y * cexp);
            f.u[3] = pkh(a1.z * cexp, a1.w * cexp);
            qf1[ks] = f.v;
        }
    }

    f32x16 zf;
#pragma unroll
    for (int r = 0; r < 16; ++r) zf[r] = 0.f;
    f32x16 oacc[2][2];  // [q-tile t][d-tile dt]
    oacc[0][0] = zf; oacc[0][1] = zf; oacc[1][0] = zf; oacc[1][1] = zf;
    float l0_ = 0.f, l1_ = 0.f;

    const size_t tbase = ((size_t)bh * 64 + half * 32) * 4096;
    // wave stages 8KB/iter: qs=0 -> K half-tile, qs=1 -> V half-tile
    const unsigned short* sgw = (qs ? Vb : Kb) + tbase;
    unsigned short* const lbase = &KV[half * 8192 + qs * 4096];

#if HAS_GLL
#define STAGE(itx, bb) { \
    const unsigned short* sp = sgw + (size_t)(itx) * 4096 + lane * 8; \
    unsigned short* ld = lbase + (bb) * 16384; \
    _Pragma("unroll") \
    for (int c = 0; c < 8; ++c) ld_lds16(sp + c * 512, ld + c * 512); }
#else
#define STAGE(itx, bb) { \
    const unsigned short* sp = sgw + (size_t)(itx) * 4096 + lane * 8; \
    unsigned short* ld = lbase + (bb) * 16384; \
    _Pragma("unroll") \
    for (int c = 0; c < 8; ++c) { \
        uint4 a = *(const uint4*)(sp + c * 512); \
        *(uint4*)&ld[c * 512 + lane * 8] = a; } }
#endif

    STAGE(0, 0);

    for (int it = 0; it < 32; ++it) {
        __syncthreads();   // buf[it&1] staged; prev readers of buf[(it+1)&1] done
        const unsigned short* Kbuf = &KV[(it & 1) * 16384 + half * 8192];
        const unsigned short* Vbuf = Kbuf + 4096;
        if (it < 31) STAGE(it + 1, (it + 1) & 1);

#pragma unroll
        for (int kt2 = 0; kt2 < 2; ++kt2) {
            // QK: one K-frag read feeds both q-tiles' MFMAs
            f32x16 sa0, sa1;
            {
                f16x8 kf = *(const f16x8*)&Kbuf[(kt2 * 4 + 0) * 512 + lane * 8];
                sa0 = __builtin_amdgcn_mfma_f32_32x32x16_f16(kf, qf0[0], zf, 0, 0, 0);
                sa1 = __builtin_amdgcn_mfma_f32_32x32x16_f16(kf, qf1[0], zf, 0, 0, 0);
#pragma unroll
                for (int ks = 1; ks < 4; ++ks) {
                    kf = *(const f16x8*)&Kbuf[(kt2 * 4 + ks) * 512 + lane * 8];
                    sa0 = __builtin_amdgcn_mfma_f32_32x32x16_f16(kf, qf0[ks], sa0, 0, 0, 0);
                    sa1 = __builtin_amdgcn_mfma_f32_32x32x16_f16(kf, qf1[ks], sa1, 0, 0, 0);
                }
            }
            // exp2 fused with f16 pack (16 packed dwords live, not 32 floats)
            unsigned u0[8], u1[8];
            float s0 = 0.f, s1 = 0.f;
#pragma unroll
            for (int j = 0; j < 8; ++j) {
                float ea = __builtin_amdgcn_exp2f(sa0[2 * j]);
                float eb = __builtin_amdgcn_exp2f(sa0[2 * j + 1]);
                s0 += ea + eb;
                u0[j] = pkh(ea, eb);
            }
#pragma unroll
            for (int j = 0; j < 8; ++j) {
                float ea = __builtin_amdgcn_exp2f(sa1[2 * j]);
                float eb = __builtin_amdgcn_exp2f(sa1[2 * j + 1]);
                s1 += ea + eb;
                u1[j] = pkh(ea, eb);
            }
            l0_ += s0; l1_ += s1;

            // PV: one V-frag pair feeds both q-tiles' MFMAs
#pragma unroll
            for (int kp = 0; kp < 2; ++kp) {
                f16x8 pb0 = xchg2(u0[4 * kp + 0], u0[4 * kp + 1], u0[4 * kp + 2], u0[4 * kp + 3], hi);
                f16x8 pb1 = xchg2(u1[4 * kp + 0], u1[4 * kp + 1], u1[4 * kp + 2], u1[4 * kp + 3], hi);
                f16x8 va0 = *(const f16x8*)&Vbuf[(0 * 4 + kt2 * 2 + kp) * 512 + lane * 8];
                f16x8 va1 = *(const f16x8*)&Vbuf[(1 * 4 + kt2 * 2 + kp) * 512 + lane * 8];
                oacc[0][0] = __builtin_amdgcn_mfma_f32_32x32x16_f16(va0, pb0, oacc[0][0], 0, 0, 0);
                oacc[0][1] = __builtin_amdgcn_mfma_f32_32x32x16_f16(va1, pb0, oacc[0][1], 0, 0, 0);
                oacc[1][0] = __builtin_amdgcn_mfma_f32_32x32x16_f16(va0, pb1, oacc[1][0], 0, 0, 0);
                oacc[1][1] = __builtin_amdgcn_mfma_f32_32x32x16_f16(va1, pb1, oacc[1][1], 0, 0, 0);
            }
        }
    }

    // half-pair reduction through LDS: region per qs = 4096 oacc + 128 l floats
    __syncthreads();
    float* red = (float*)KV + qs * 4224;
    if (half) {
#pragma unroll
        for (int t = 0; t < 2; ++t)
#pragma unroll
            for (int dt = 0; dt < 2; ++dt)
#pragma unroll
                for (int g = 0; g < 4; ++g) {
                    float4 v;
                    v.x = oacc[t][dt][g * 4 + 0];
                    v.y = oacc[t][dt][g * 4 + 1];
                    v.z = oacc[t][dt][g * 4 + 2];
                    v.w = oacc[t][dt][g * 4 + 3];
                    *(float4*)&red[((t * 2 + dt) * 4 + g) * 256 + lane * 4] = v;
                }
        red[4096 + lane] = l0_;
        red[4096 + 64 + lane] = l1_;
    }
    __syncthreads();
    if (!half) {
#pragma unroll
        for (int t = 0; t < 2; ++t)
#pragma unroll
            for (int dt = 0; dt < 2; ++dt)
#pragma unroll
                for (int g = 0; g < 4; ++g) {
                    float4 v = *(const float4*)&red[((t * 2 + dt) * 4 + g) * 256 + lane * 4];
                    oacc[t][dt][g * 4 + 0] += v.x;
                    oacc[t][dt][g * 4 + 1] += v.y;
                    oacc[t][dt][g * 4 + 2] += v.z;
                    oacc[t][dt][g * 4 + 3] += v.w;
                }
        l0_ += red[4096 + lane];
        l1_ += red[4096 + 64 + lane];
        l0_ += __shfl_xor(l0_, 32);
        l1_ += __shfl_xor(l1_, 32);
#pragma unroll
        for (int t = 0; t < 2; ++t) {
            const float li = 1.f / (t ? l1_ : l0_);
            const int gm = b * 128 + qt * 4 + qs * 2 + t;
#pragma unroll
            for (int ksg = 0; ksg < 4; ++ksg) {
                const int dt = ksg >> 1, k2 = ksg & 1;
                unsigned g0x = pkh(oacc[t][dt][8 * k2 + 0] * li, oacc[t][dt][8 * k2 + 1] * li);
                unsigned g0y = pkh(oacc[t][dt][8 * k2 + 2] * li, oacc[t][dt][8 * k2 + 3] * li);
                unsigned g1x = pkh(oacc[t][dt][8 * k2 + 4] * li, oacc[t][dt][8 * k2 + 5] * li);
                unsigned g1y = pkh(oacc[t][dt][8 * k2 + 6] * li, oacc[t][dt][8 * k2 + 7] * li);
                f16x8 frag = xchg2(g0x, g0y, g1x, g1y, hi);
                union { f16x8 v; uint4 u; } fu; fu.v = frag;
                *(uint4*)&ObA[((size_t)(gm * 32 + h * 4 + ksg) * 64 + lane) * 8] = fu.u;
            }
        }
    }
}

// ---------- projection GEMM: out = A @ W + b (A,W fragment-ordered f16) ----------
__global__ __launch_bounds__(256) void proj_kernel(
    const unsigned short* __restrict__ ObA,  // [256][32][64][8]
    const unsigned short* __restrict__ Wb,   // [16][32][64][8]
    const float* __restrict__ bias,
    float* __restrict__ out) {
    __shared__ __align__(16) unsigned short Ash[8192];
    __shared__ __align__(16) unsigned short Wsh[4096];

    const int mt = blockIdx.x;
    const int nt = blockIdx.y;
    const int tid = threadIdx.x;
    const int w = tid >> 6;
    const int lane = tid & 63;
    const int q = lane & 31;
    const int hi = lane >> 5;

    f32x16 acc[2];
#pragma unroll
    for (int t = 0; t < 2; ++t)
#pragma unroll
        for (int r = 0; r < 16; ++r) acc[t][r] = 0.f;

    for (int kt = 0; kt < 8; ++kt) {
        __syncthreads();
#pragma unroll
        for (int i = 0; i < 4; ++i) {
            int ci = (tid >> 6) + i * 4;
            int ml = ci >> 2, ksl = ci & 3;
            *(uint4*)&Ash[ci * 512 + lane * 8] =
                *(const uint4*)(ObA + (((size_t)(mt * 4 + ml) * 32 + kt * 4 + ksl) * 64 + lane) * 8);
        }
#pragma unroll
        for (int i = 0; i < 2; ++i) {
            int ci = (tid >> 6) + i * 4;
            int ntl = ci >> 2, ksl = ci & 3;
            *(uint4*)&Wsh[ci * 512 + lane * 8] =
                *(const uint4*)(Wb + (((size_t)(nt * 2 + ntl) * 32 + kt * 4 + ksl) * 64 + lane) * 8);
        }
        __syncthreads();

#pragma unroll
        for (int ks = 0; ks < 4; ++ks) {
            f16x8 a  = *(const f16x8*)&Ash[(w * 4 + ks) * 512 + lane * 8];
            f16x8 b0 = *(const f16x8*)&Wsh[(0 * 4 + ks) * 512 + lane * 8];
            f16x8 b1 = *(const f16x8*)&Wsh[(4 + ks) * 512 + lane * 8];
            acc[0] = __builtin_amdgcn_mfma_f32_32x32x16_f16(a, b0, acc[0], 0, 0, 0);
            acc[1] = __builtin_amdgcn_mfma_f32_32x32x16_f16(a, b1, acc[1], 0, 0, 0);
        }
    }

#pragma unroll
    for (int ntl = 0; ntl < 2; ++ntl) {
        int col = nt * 64 + ntl * 32 + q;
        float bv = bias[col];
#pragma unroll
        for (int reg = 0; reg < 16; ++reg) {
            int row = mt * 128 + w * 32 + (reg & 3) + 8 * (reg >> 2) + 4 * hi;
            out[(size_t)row * Dn + col] = acc[ntl][reg] + bv;
        }
    }
}

extern "C" void kernel_launch(void* const* d_in, const int* in_sizes, int n_in,
                              void* d_out, int out_size, void* d_ws, size_t ws_size,
                              hipStream_t stream) {
    const float* Q = (const float*)d_in[0];
    const float* K = (const float*)d_in[1];
    const float* V = (const float*)d_in[2];
    const float* W = (const float*)d_in[3];
    const float* bo = (const float*)d_in[4];
    float* out = (float*)d_out;

    char* ws = (char*)d_ws;
    unsigned short* Kb  = (unsigned short*)(ws);                 // 8 MB
    unsigned short* Vb  = (unsigned short*)(ws + 8388608);       // 8 MB
    unsigned short* Wb  = (unsigned short*)(ws + 16777216);      // 512 KB
    unsigned short* ObA = (unsigned short*)(ws + 17301504);      // 8 MB

    prep_kernel<<<2176, 256, 0, stream>>>(K, V, W, Kb, Vb, Wb);
    attn_kernel<<<dim3(32, 16), 256, 0, stream>>>(Q, Kb, Vb, ObA);
    proj_kernel<<<dim3(64, 8), 256, 0, stream>>>(ObA, Wb, bo, out);
}